// Round 7
// baseline (538.768 us; speedup 1.0000x reference)
//
#include <hip/hip_runtime.h>
#include <stdint.h>

#define BATCH 524288
#define OBSD  64

typedef short v8s __attribute__((ext_vector_type(8)));
typedef float v4f __attribute__((ext_vector_type(4)));

union U8 { int4 i4; v8s v; uint32_t u[4]; };

// gfx950 packed fp32->bf16 convert (RNE)
__device__ __forceinline__ uint32_t pk2(float a, float b) {
  uint32_t r;
  asm("v_cvt_pk_bf16_f32 %0, %1, %2" : "=v"(r) : "v"(a), "v"(b));
  return r;
}

// ---- prep: build packed weight image in d_ws ----
// Wall (uint16_t elems):
//   [0,16384)      W2t row-major bf16
//   [16384,32768)  W2p row-major bf16
//   [32768,40960)  W1t frag-order: frag(rt,ks) 512 elems at (rt*2+ks)*512 + lane*8
//   [40960,49152)  W1p frag-order
//   [49152,65536)  W3t frag-order: (rt*4+ks)*512 + lane*8
//   [65536,81920)  -W3p frag-order (pre-negated)
__global__ void rnd_prep(const float* __restrict__ tW1, const float* __restrict__ tW2,
                         const float* __restrict__ tW3, const float* __restrict__ pW1,
                         const float* __restrict__ pW2, const float* __restrict__ pW3,
                         uint16_t* __restrict__ Wall, float* __restrict__ sums) {
  int g = blockIdx.x * 256 + threadIdx.x;   // grid 40*256 = 10240, 8 elems each
  if (g < 2) sums[g] = 0.0f;
  const float* src;
  uint16_t* dst;
  float sgn = 1.f;
  if (g < 4096) {                            // W2t | W2p row-major
    src = (g < 2048) ? (tW2 + g * 8) : (pW2 + g * 8 - 16384);
    dst = Wall + g * 8;
  } else if (g < 6144) {                     // W1 frags
    int u = g - 4096;
    int m = u >> 10; u &= 1023;
    int rt = u >> 7, ks = (u >> 6) & 1, lane = u & 63;
    int n = lane & 15, qq = lane >> 4;
    src = (m ? pW1 : tW1) + (rt * 16 + n) * 64 + ks * 32 + qq * 8;
    dst = Wall + 32768 + m * 8192 + u * 8;
  } else {                                   // W3 frags (predictor negated)
    int u = g - 6144;
    int m = u >> 11; u &= 2047;
    int rt = u >> 8, ks = (u >> 6) & 3, lane = u & 63;
    int n = lane & 15, qq = lane >> 4;
    src = (m ? pW3 : tW3) + (rt * 16 + n) * 128 + ks * 32 + qq * 8;
    sgn = m ? -1.f : 1.f;
    dst = Wall + 49152 + m * 16384 + u * 8;
  }
  float4 f0 = *(const float4*)src, f1 = *(const float4*)(src + 4);
  U8 u8;
  u8.u[0] = pk2(sgn * f0.x, sgn * f0.y); u8.u[1] = pk2(sgn * f0.z, sgn * f0.w);
  u8.u[2] = pk2(sgn * f1.x, sgn * f1.y); u8.u[3] = pk2(sgn * f1.z, sgn * f1.w);
  *(int4*)dst = u8.i4;
}

// ---- main: W2 pair resident in 64KiB swizzled LDS (staged once, 1 barrier);
//      W1/W3 frag-order global loads (coalesced, L1/L2-hot); 4 tiles per wave
//      with NO in-loop barriers; Welford in regs, reduced once at the end. ----
__global__ __launch_bounds__(256, 2) void rnd_main(
    const float* __restrict__ obs, const uint16_t* __restrict__ Wall,
    const float* __restrict__ b1t, const float* __restrict__ b2t,
    const float* __restrict__ b1p, const float* __restrict__ b2p,
    const float* __restrict__ b3t, const float* __restrict__ b3p,
    float* __restrict__ rewards, float* __restrict__ sums) {
  extern __shared__ uint16_t Wl[];  // 65536 B: W2t swz @0, W2p swz @16384
  const int t    = threadIdx.x;
  const int lane = t & 63;
  const int wv   = t >> 6;
  const int n    = lane & 15;
  const int q    = lane >> 4;

  // ---- stage W2 pair, swizzled: chunk c of row d at d*128 + ((c+d)&15)*8 ----
  {
    // thread t writes chunks g=i*256+t: d=i*16+(t>>4), c=t&15; slot=((t&15)+(t>>4))&15
    uint16_t* wb = Wl + (t >> 4) * 128 + ((((t & 15) + (t >> 4)) & 15) << 3);
    const uint16_t* gsrc = Wall + t * 8;
    #pragma unroll
    for (int m = 0; m < 2; ++m)
      #pragma unroll
      for (int i = 0; i < 8; ++i) {
        U8 u; u.i4 = *(const int4*)(gsrc + m * 16384 + i * 2048);
        *(int4*)(wb + m * 16384 + i * 2048) = u.i4;
      }
  }
  // per-lane swizzled read bases: frag row d=rt*16+n, chunk c=ks*4+q,
  // slot=(c+d)&15=(ks*4+q+n)&15  (rt*16 vanishes mod 16)
  const uint16_t* a2k0 = Wl + n * 128 + ((((0 * 4) + q + n) & 15) << 3);
  const uint16_t* a2k1 = Wl + n * 128 + ((((1 * 4) + q + n) & 15) << 3);
  const uint16_t* a2k2 = Wl + n * 128 + ((((2 * 4) + q + n) & 15) << 3);
  const uint16_t* a2k3 = Wl + n * 128 + ((((3 * 4) + q + n) & 15) << 3);
  const uint16_t* wb1 = Wall + 32768 + lane * 8;  // W1t frags (W1p at +8192)
  const uint16_t* wb3 = Wall + 49152 + lane * 8;  // W3t frags (W3n at +16384)
  __syncthreads();   // the ONLY staging barrier

  auto afragW2 = [&](int m, int rt, int ks) -> v8s {
    const uint16_t* b = (ks == 0) ? a2k0 : (ks == 1) ? a2k1 : (ks == 2) ? a2k2 : a2k3;
    U8 u; u.i4 = *(const int4*)(b + m * 16384 + rt * 2048);
    return u.v;
  };
  auto bias_init = [&](const float* b, v4f (&acc)[8][2]) {
    #pragma unroll
    for (int rt = 0; rt < 8; ++rt) {
      float4 bv = *(const float4*)(b + rt * 16 + q * 4);
      v4f c; c[0] = bv.x; c[1] = bv.y; c[2] = bv.z; c[3] = bv.w;
      acc[rt][0] = c; acc[rt][1] = c;
    }
  };
  auto pack_out = [&](v4f (&acc)[8][2], uint32_t (&P)[8][2][2]) {
    #pragma unroll
    for (int rt = 0; rt < 8; ++rt)
      #pragma unroll
      for (int ct = 0; ct < 2; ++ct) {
        v4f a = acc[rt][ct];
        a[0] = fmaxf(a[0], 0.f); a[1] = fmaxf(a[1], 0.f);
        a[2] = fmaxf(a[2], 0.f); a[3] = fmaxf(a[3], 0.f);
        P[rt][ct][0] = pk2(a[0], a[1]);
        P[rt][ct][1] = pk2(a[2], a[3]);
      }
  };
  auto bfrag_from = [&](uint32_t (&P)[8][2][2], int ks, int ct) -> v8s {
    uint32_t x0 = P[2 * ks][ct][0],     x1 = P[2 * ks][ct][1];
    uint32_t y0 = P[2 * ks + 1][ct][0], y1 = P[2 * ks + 1][ct][1];
    asm("v_permlane32_swap_b32 %0, %1" : "+v"(x0), "+v"(y0));
    asm("v_permlane16_swap_b32 %0, %1" : "+v"(x0), "+v"(y0));
    asm("v_permlane32_swap_b32 %0, %1" : "+v"(x1), "+v"(y1));
    asm("v_permlane16_swap_b32 %0, %1" : "+v"(x1), "+v"(y1));
    U8 u; u.u[0] = x0; u.u[1] = x1; u.u[2] = y0; u.u[3] = y1;
    return u.v;
  };

  float sAcc = 0.f, ssAcc = 0.f;
  #pragma unroll 1
  for (int it = 0; it < 4; ++it) {
    const int tile = it * 4096 + blockIdx.x * 4 + wv;
    const int s0   = tile * 32;

    // obs load + pack
    v8s obf[2][2];
    #pragma unroll
    for (int ct = 0; ct < 2; ++ct)
      #pragma unroll
      for (int ks = 0; ks < 2; ++ks) {
        const float* p = obs + (size_t)(s0 + ct * 16 + n) * OBSD + ks * 32 + q * 8;
        float4 f0 = *(const float4*)p;
        float4 f1 = *(const float4*)(p + 4);
        U8 u;
        u.u[0] = pk2(f0.x, f0.y); u.u[1] = pk2(f0.z, f0.w);
        u.u[2] = pk2(f1.x, f1.y); u.u[3] = pk2(f1.z, f1.w);
        obf[ct][ks] = u.v;
      }

    uint32_t Pt[8][2][2], Pa[8][2][2];
    // ---- L1 (W1 frags from global, frag-order) ----
    #pragma unroll
    for (int m = 0; m < 2; ++m) {
      v4f acc[8][2];
      bias_init(m ? b1p : b1t, acc);
      #pragma unroll
      for (int ks = 0; ks < 2; ++ks)
        #pragma unroll
        for (int rt = 0; rt < 8; ++rt) {
          U8 u; u.i4 = *(const int4*)(wb1 + m * 8192 + (rt * 2 + ks) * 512);
          acc[rt][0] = __builtin_amdgcn_mfma_f32_16x16x32_bf16(u.v, obf[0][ks], acc[rt][0], 0, 0, 0);
          acc[rt][1] = __builtin_amdgcn_mfma_f32_16x16x32_bf16(u.v, obf[1][ks], acc[rt][1], 0, 0, 0);
        }
      pack_out(acc, m ? Pa : Pt);
    }
    // ---- L2 (W2 pair from swizzled LDS) ----
    #pragma unroll
    for (int m = 0; m < 2; ++m) {
      uint32_t (&P)[8][2][2] = m ? Pa : Pt;
      v4f acc[8][2];
      bias_init(m ? b2p : b2t, acc);
      #pragma unroll
      for (int ks = 0; ks < 4; ++ks) {
        v8s bf0 = bfrag_from(P, ks, 0), bf1 = bfrag_from(P, ks, 1);
        #pragma unroll
        for (int rt = 0; rt < 8; ++rt) {
          v8s af = afragW2(m, rt, ks);
          acc[rt][0] = __builtin_amdgcn_mfma_f32_16x16x32_bf16(af, bf0, acc[rt][0], 0, 0, 0);
          acc[rt][1] = __builtin_amdgcn_mfma_f32_16x16x32_bf16(af, bf1, acc[rt][1], 0, 0, 0);
        }
      }
      pack_out(acc, P);
    }
    // ---- L3: acc = (b3t-b3p) + W3t*H2t + (-W3p)*H2p ----
    v4f acc[8][2];
    #pragma unroll
    for (int rt = 0; rt < 8; ++rt) {
      float4 bt = *(const float4*)(b3t + rt * 16 + q * 4);
      float4 bp = *(const float4*)(b3p + rt * 16 + q * 4);
      v4f c; c[0] = bt.x - bp.x; c[1] = bt.y - bp.y; c[2] = bt.z - bp.z; c[3] = bt.w - bp.w;
      acc[rt][0] = c; acc[rt][1] = c;
    }
    #pragma unroll
    for (int m = 0; m < 2; ++m) {
      uint32_t (&P)[8][2][2] = m ? Pa : Pt;
      #pragma unroll
      for (int ks = 0; ks < 4; ++ks) {
        v8s bf0 = bfrag_from(P, ks, 0), bf1 = bfrag_from(P, ks, 1);
        #pragma unroll
        for (int rt = 0; rt < 8; ++rt) {
          U8 u; u.i4 = *(const int4*)(wb3 + m * 16384 + (rt * 4 + ks) * 512);
          acc[rt][0] = __builtin_amdgcn_mfma_f32_16x16x32_bf16(u.v, bf0, acc[rt][0], 0, 0, 0);
          acc[rt][1] = __builtin_amdgcn_mfma_f32_16x16x32_bf16(u.v, bf1, acc[rt][1], 0, 0, 0);
        }
      }
    }

    // ---- epilogue: reward = mean over 128 out-dims of diff^2 ----
    float p0 = 0.f, p1 = 0.f;
    #pragma unroll
    for (int rt = 0; rt < 8; ++rt) {
      v4f a0 = acc[rt][0], a1 = acc[rt][1];
      p0 += a0[0]*a0[0] + a0[1]*a0[1] + a0[2]*a0[2] + a0[3]*a0[3];
      p1 += a1[0]*a1[0] + a1[1]*a1[1] + a1[2]*a1[2] + a1[3]*a1[3];
    }
    p0 += __shfl_xor(p0, 32); p0 += __shfl_xor(p0, 16);
    p1 += __shfl_xor(p1, 32); p1 += __shfl_xor(p1, 16);
    float r0 = p0 * (1.0f / 128.0f), r1 = p1 * (1.0f / 128.0f);
    if (q == 0) {
      rewards[s0 + n]      = r0;
      rewards[s0 + 16 + n] = r1;
    }
    sAcc  += r0 + r1;               // all 64 lanes: 4x duplication, scaled later
    ssAcc += r0 * r0 + r1 * r1;
  }

  // ---- final reduction: full-wave butterfly, LDS scratch reuses Wl ----
  #pragma unroll
  for (int d = 1; d < 64; d <<= 1) {
    sAcc  += __shfl_xor(sAcc, d);
    ssAcc += __shfl_xor(ssAcc, d);
  }
  __syncthreads();                  // all weight reads done; Wl reusable
  float* red = (float*)Wl;
  if (lane == 0) { red[wv] = sAcc; red[8 + wv] = ssAcc; }
  __syncthreads();
  if (t == 0) {
    atomicAdd(&sums[0], 0.25f * (red[0] + red[1] + red[2] + red[3]));
    atomicAdd(&sums[1], 0.25f * (red[8] + red[9] + red[10] + red[11]));
  }
}

// ---- normalize: Chan-merge with running stats ----
__global__ void rnd_norm(const float* __restrict__ rewards, const float* __restrict__ sums,
                         const float* __restrict__ rm, const float* __restrict__ rm2,
                         const float* __restrict__ rc, float* __restrict__ out) {
  float S = sums[0], SS = sums[1];
  float nb = (float)BATCH;
  float bm = S / nb;
  float bm2 = SS - nb * bm * bm;
  float cnt = rc[0];
  float newc = cnt + nb;
  float delta = bm - rm[0];
  float newmean = rm[0] + delta * nb / newc;
  float newm2 = rm2[0] + bm2 + delta * delta * cnt * nb / newc;
  float sd = (newc > 1.f) ? sqrtf(newm2 / (newc - 1.f)) : 1.f;
  float inv = 1.f / (sd + 1e-8f);
  int i = (blockIdx.x * 256 + threadIdx.x) * 4;
  float4 r = *(const float4*)(rewards + i);
  float4 o;
  o.x = (r.x - newmean) * inv; o.y = (r.y - newmean) * inv;
  o.z = (r.z - newmean) * inv; o.w = (r.w - newmean) * inv;
  *(float4*)(out + i) = o;
}

extern "C" void kernel_launch(void* const* d_in, const int* in_sizes, int n_in,
                              void* d_out, int out_size, void* d_ws, size_t ws_size,
                              hipStream_t stream) {
  const float* obs = (const float*)d_in[0];
  const float* rm  = (const float*)d_in[1];
  const float* rm2 = (const float*)d_in[2];
  const float* rc  = (const float*)d_in[3];
  const float* tW1 = (const float*)d_in[4];
  const float* tb1 = (const float*)d_in[5];
  const float* tW2 = (const float*)d_in[6];
  const float* tb2 = (const float*)d_in[7];
  const float* tW3 = (const float*)d_in[8];
  const float* tb3 = (const float*)d_in[9];
  const float* pW1 = (const float*)d_in[10];
  const float* pb1 = (const float*)d_in[11];
  const float* pW2 = (const float*)d_in[12];
  const float* pb2 = (const float*)d_in[13];
  const float* pW3 = (const float*)d_in[14];
  const float* pb3 = (const float*)d_in[15];

  float*    sums    = (float*)d_ws;
  float*    rewards = (float*)((char*)d_ws + 256);
  uint16_t* Wall    = (uint16_t*)((char*)d_ws + 256 + (size_t)BATCH * 4);

  (void)hipFuncSetAttribute((const void*)rnd_main,
                            hipFuncAttributeMaxDynamicSharedMemorySize, 65536);

  rnd_prep<<<40, 256, 0, stream>>>(tW1, tW2, tW3, pW1, pW2, pW3, Wall, sums);
  rnd_main<<<1024, 256, 65536, stream>>>(obs, Wall, tb1, tb2, pb1, pb2, tb3, pb3,
                                         rewards, sums);
  rnd_norm<<<BATCH / 1024, 256, 0, stream>>>(rewards, sums, rm, rm2, rc, (float*)d_out);
}

// Round 8
// 305.731 us; speedup vs baseline: 1.7622x; 1.7622x over previous
//
#include <hip/hip_runtime.h>
#include <stdint.h>

#define BATCH 524288
#define OBSD  64

typedef short v8s __attribute__((ext_vector_type(8)));
typedef float v4f __attribute__((ext_vector_type(4)));

union U8 { int4 i4; v8s v; uint32_t u[4]; };

// gfx950 packed fp32->bf16 convert (RNE)
__device__ __forceinline__ uint32_t pk2(float a, float b) {
  uint32_t r;
  asm("v_cvt_pk_bf16_f32 %0, %1, %2" : "=v"(r) : "v"(a), "v"(b));
  return r;
}

// async global->LDS, 16 B per lane (width=16). LDS dst is wave-uniform base;
// HW scatters lane i to dst + i*16.
__device__ __forceinline__ void glds16(const uint16_t* g, uint16_t* l) {
  __builtin_amdgcn_global_load_lds(
      (const __attribute__((address_space(1))) uint32_t*)g,
      (__attribute__((address_space(3))) uint32_t*)l, 16, 0, 0);
}

// ---- prep: weights -> bf16 frag-order image (W3p negated) ----
// Wall (uint16_t elems), all frag-order (frag = 512 elems, lane-major):
//   W1t@0      frag(rt,ks2): (rt*2+ks)*512 + lane*8      [8192]
//   W1p@8192   same                                       [8192]
//   W2t@16384  frag(rt,ks4): (rt*4+ks)*512 + lane*8      [16384]
//   W2p@32768                                             [16384]
//   W3t@49152                                             [16384]
//   W3n@65536  (pre-negated pW3)                          [16384]
__global__ void rnd_prep(const float* __restrict__ tW1, const float* __restrict__ tW2,
                         const float* __restrict__ tW3, const float* __restrict__ pW1,
                         const float* __restrict__ pW2, const float* __restrict__ pW3,
                         uint16_t* __restrict__ Wall, float* __restrict__ sums) {
  int g = blockIdx.x * 256 + threadIdx.x;   // 40*256 = 10240 units x 8 elems
  if (g < 2) sums[g] = 0.0f;
  const float* src;
  uint16_t* dst;
  float sgn = 1.f;
  if (g < 2048) {                            // W1 frags (verified R7 pattern)
    int u = g;
    int m = u >> 10; u &= 1023;
    int rt = u >> 7, ks = (u >> 6) & 1, lane = u & 63;
    int n = lane & 15, qq = lane >> 4;
    src = (m ? pW1 : tW1) + (rt * 16 + n) * 64 + ks * 32 + qq * 8;
    dst = Wall + m * 8192 + u * 8;
  } else if (g < 6144) {                     // W2 frags (same 128x128 pattern)
    int u = g - 2048;
    int m = u >> 11; u &= 2047;
    int rt = u >> 8, ks = (u >> 6) & 3, lane = u & 63;
    int n = lane & 15, qq = lane >> 4;
    src = (m ? pW2 : tW2) + (rt * 16 + n) * 128 + ks * 32 + qq * 8;
    dst = Wall + 16384 + m * 16384 + u * 8;
  } else {                                   // W3 frags (predictor negated)
    int u = g - 6144;
    int m = u >> 11; u &= 2047;
    int rt = u >> 8, ks = (u >> 6) & 3, lane = u & 63;
    int n = lane & 15, qq = lane >> 4;
    src = (m ? pW3 : tW3) + (rt * 16 + n) * 128 + ks * 32 + qq * 8;
    sgn = m ? -1.f : 1.f;
    dst = Wall + 49152 + m * 16384 + u * 8;
  }
  float4 f0 = *(const float4*)src, f1 = *(const float4*)(src + 4);
  U8 u8;
  u8.u[0] = pk2(sgn * f0.x, sgn * f0.y); u8.u[1] = pk2(sgn * f0.z, sgn * f0.w);
  u8.u[2] = pk2(sgn * f1.x, sgn * f1.y); u8.u[3] = pk2(sgn * f1.z, sgn * f1.w);
  *(int4*)dst = u8.i4;
}

// ---- main: 3x16KB LDS ring, async glds prefetch issued right after each
// barrier (consumed 2+ phases later -> barrier vmcnt drain is free), frag-order
// conflict-free ds_read_b128 with zero address VALU. ----
__global__ __launch_bounds__(256, 3) void rnd_main(
    const float* __restrict__ obs, const uint16_t* __restrict__ Wall,
    const float* __restrict__ b1t, const float* __restrict__ b2t,
    const float* __restrict__ b1p, const float* __restrict__ b2p,
    const float* __restrict__ b3t, const float* __restrict__ b3p,
    float* __restrict__ rewards, float* __restrict__ sums) {
  extern __shared__ __align__(16) uint16_t Wl[];  // 49152 B = 3 x 16 KB
  const int t    = threadIdx.x;
  const int lane = t & 63;
  const int wv   = t >> 6;
  const int n    = lane & 15;
  const int q    = lane >> 4;
  const int s0   = (blockIdx.x * 4 + wv) * 32;

  // chunk srcs (elem offsets), ring buffer byte offsets
  // c0 W1t, c1 W1p, c2 W2t.lo, c3 W2t.hi, c4 W2p.lo, c5 W2p.hi,
  // c6 W3t.lo, c7 W3t.hi, c8 W3n.lo, c9 W3n.hi;  ck -> buf (k%3)
  const uint16_t* gsrc = Wall + wv * 2048 + lane * 8;   // per-chunk: + off + j*512
  uint16_t*       lbas = Wl + wv * 2048;                // elems; + bufoff/2 + j*512
  auto stage = [&](int chunkElemOff, int bufByteOff) {
    #pragma unroll
    for (int j = 0; j < 4; ++j)
      glds16(gsrc + chunkElemOff + j * 512, lbas + bufByteOff / 2 + j * 512);
  };

  const uint16_t* rb = Wl + lane * 8;  // frag read base; +bufoff/2 + frag*512

  // ---- kick off first three chunks + obs loads ----
  stage(0, 0);            // c0 -> b0
  stage(8192, 16384);     // c1 -> b1
  stage(16384, 32768);    // c2 -> b2
  float4 of[8];
  #pragma unroll
  for (int ct = 0; ct < 2; ++ct)
    #pragma unroll
    for (int ks = 0; ks < 2; ++ks) {
      const float* p = obs + (size_t)(s0 + ct * 16 + n) * OBSD + ks * 32 + q * 8;
      of[(ct * 2 + ks) * 2 + 0] = *(const float4*)p;
      of[(ct * 2 + ks) * 2 + 1] = *(const float4*)(p + 4);
    }
  v8s obf[2][2];
  #pragma unroll
  for (int ct = 0; ct < 2; ++ct)
    #pragma unroll
    for (int ks = 0; ks < 2; ++ks) {
      float4 f0 = of[(ct * 2 + ks) * 2 + 0];
      float4 f1 = of[(ct * 2 + ks) * 2 + 1];
      U8 u;
      u.u[0] = pk2(f0.x, f0.y); u.u[1] = pk2(f0.z, f0.w);
      u.u[2] = pk2(f1.x, f1.y); u.u[3] = pk2(f1.z, f1.w);
      obf[ct][ks] = u.v;
    }

  auto bias_init = [&](const float* b, v4f (&acc)[8][2]) {
    #pragma unroll
    for (int rt = 0; rt < 8; ++rt) {
      float4 bv = *(const float4*)(b + rt * 16 + q * 4);
      v4f c; c[0] = bv.x; c[1] = bv.y; c[2] = bv.z; c[3] = bv.w;
      acc[rt][0] = c; acc[rt][1] = c;
    }
  };
  auto pack_out = [&](v4f (&acc)[8][2], uint32_t (&P)[8][2][2]) {
    #pragma unroll
    for (int rt = 0; rt < 8; ++rt)
      #pragma unroll
      for (int ct = 0; ct < 2; ++ct) {
        v4f a = acc[rt][ct];
        a[0] = fmaxf(a[0], 0.f); a[1] = fmaxf(a[1], 0.f);
        a[2] = fmaxf(a[2], 0.f); a[3] = fmaxf(a[3], 0.f);
        P[rt][ct][0] = pk2(a[0], a[1]);
        P[rt][ct][1] = pk2(a[2], a[3]);
      }
  };
  auto bfrag_from = [&](uint32_t (&P)[8][2][2], int ks, int ct) -> v8s {
    uint32_t x0 = P[2 * ks][ct][0],     x1 = P[2 * ks][ct][1];
    uint32_t y0 = P[2 * ks + 1][ct][0], y1 = P[2 * ks + 1][ct][1];
    asm("v_permlane32_swap_b32 %0, %1" : "+v"(x0), "+v"(y0));
    asm("v_permlane16_swap_b32 %0, %1" : "+v"(x0), "+v"(y0));
    asm("v_permlane32_swap_b32 %0, %1" : "+v"(x1), "+v"(y1));
    asm("v_permlane16_swap_b32 %0, %1" : "+v"(x1), "+v"(y1));
    U8 u; u.u[0] = x0; u.u[1] = x1; u.u[2] = y0; u.u[3] = y1;
    return u.v;
  };
  auto layer1 = [&](int bufOff, const float* b, uint32_t (&P)[8][2][2]) {
    v4f acc[8][2];
    bias_init(b, acc);
    #pragma unroll
    for (int ks = 0; ks < 2; ++ks)
      #pragma unroll
      for (int rt = 0; rt < 8; ++rt) {
        U8 u; u.i4 = *(const int4*)(rb + bufOff / 2 + (rt * 2 + ks) * 512);
        acc[rt][0] = __builtin_amdgcn_mfma_f32_16x16x32_bf16(u.v, obf[0][ks], acc[rt][0], 0, 0, 0);
        acc[rt][1] = __builtin_amdgcn_mfma_f32_16x16x32_bf16(u.v, obf[1][ks], acc[rt][1], 0, 0, 0);
      }
    pack_out(acc, P);
  };
  // half of a 128x128 layer: rts rtBase..rtBase+3 from one 16KB chunk
  auto half128 = [&](int bufOff, int rtBase, uint32_t (&Pin)[8][2][2], v4f (&acc)[8][2]) {
    #pragma unroll
    for (int ks = 0; ks < 4; ++ks) {
      v8s bf0 = bfrag_from(Pin, ks, 0), bf1 = bfrag_from(Pin, ks, 1);
      #pragma unroll
      for (int r = 0; r < 4; ++r) {
        U8 u; u.i4 = *(const int4*)(rb + bufOff / 2 + (r * 4 + ks) * 512);
        acc[rtBase + r][0] = __builtin_amdgcn_mfma_f32_16x16x32_bf16(u.v, bf0, acc[rtBase + r][0], 0, 0, 0);
        acc[rtBase + r][1] = __builtin_amdgcn_mfma_f32_16x16x32_bf16(u.v, bf1, acc[rtBase + r][1], 0, 0, 0);
      }
    }
  };

  uint32_t Pt[8][2][2], Pa[8][2][2];

  __syncthreads();                               // c0..c2 ready
  layer1(0, b1t, Pt);                            // ph0 (b0=c0)
  __syncthreads(); stage(24576, 0);              // c3 -> b0
  layer1(16384, b1p, Pa);                        // ph1 (b1=c1)
  __syncthreads(); stage(32768, 16384);          // c4 -> b1

  v4f a2[8][2];
  bias_init(b2t, a2);
  half128(32768, 0, Pt, a2);                     // ph2 (b2=c2: W2t.lo)
  __syncthreads(); stage(40960, 32768);          // c5 -> b2
  half128(0, 4, Pt, a2);                         // ph3 (b0=c3: W2t.hi)
  pack_out(a2, Pt);
  __syncthreads(); stage(49152, 0);              // c6 -> b0

  bias_init(b2p, a2);
  half128(16384, 0, Pa, a2);                     // ph4 (b1=c4: W2p.lo)
  __syncthreads(); stage(57344, 16384);          // c7 -> b1
  half128(32768, 4, Pa, a2);                     // ph5 (b2=c5: W2p.hi)
  pack_out(a2, Pa);
  __syncthreads(); stage(65536, 32768);          // c8 -> b2

  v4f acc[8][2];
  #pragma unroll
  for (int rt = 0; rt < 8; ++rt) {
    float4 bt = *(const float4*)(b3t + rt * 16 + q * 4);
    float4 bp = *(const float4*)(b3p + rt * 16 + q * 4);
    v4f c; c[0] = bt.x - bp.x; c[1] = bt.y - bp.y; c[2] = bt.z - bp.z; c[3] = bt.w - bp.w;
    acc[rt][0] = c; acc[rt][1] = c;
  }
  half128(0, 0, Pt, acc);                        // ph6 (b0=c6: W3t.lo)
  __syncthreads(); stage(73728, 0);              // c9 -> b0
  half128(16384, 4, Pt, acc);                    // ph7 (b1=c7: W3t.hi)
  __syncthreads();
  half128(32768, 0, Pa, acc);                    // ph8 (b2=c8: W3n.lo)
  __syncthreads();
  half128(0, 4, Pa, acc);                        // ph9 (b0=c9: W3n.hi)

  // ---- epilogue: reward = mean over 128 out-dims of diff^2 ----
  float p0 = 0.f, p1 = 0.f;
  #pragma unroll
  for (int rt = 0; rt < 8; ++rt) {
    v4f a0 = acc[rt][0], a1 = acc[rt][1];
    p0 += a0[0]*a0[0] + a0[1]*a0[1] + a0[2]*a0[2] + a0[3]*a0[3];
    p1 += a1[0]*a1[0] + a1[1]*a1[1] + a1[2]*a1[2] + a1[3]*a1[3];
  }
  p0 += __shfl_xor(p0, 32); p0 += __shfl_xor(p0, 16);
  p1 += __shfl_xor(p1, 32); p1 += __shfl_xor(p1, 16);
  float r0 = p0 * (1.0f / 128.0f), r1 = p1 * (1.0f / 128.0f);
  if (q == 0) {
    rewards[s0 + n]      = r0;
    rewards[s0 + 16 + n] = r1;
  }
  float s = r0 + r1, ss = r0 * r0 + r1 * r1;
  s  += __shfl_xor(s, 8);  s  += __shfl_xor(s, 4);  s  += __shfl_xor(s, 2);  s  += __shfl_xor(s, 1);
  ss += __shfl_xor(ss, 8); ss += __shfl_xor(ss, 4); ss += __shfl_xor(ss, 2); ss += __shfl_xor(ss, 1);
  __syncthreads();                  // all reads of Wl done; reuse as scratch
  float* red = (float*)Wl;
  if (lane == 0) { red[wv] = s; red[8 + wv] = ss; }
  __syncthreads();
  if (t == 0) {
    atomicAdd(&sums[0], red[0] + red[1] + red[2] + red[3]);
    atomicAdd(&sums[1], red[8] + red[9] + red[10] + red[11]);
  }
}

// ---- normalize: Chan-merge with running stats ----
__global__ void rnd_norm(const float* __restrict__ rewards, const float* __restrict__ sums,
                         const float* __restrict__ rm, const float* __restrict__ rm2,
                         const float* __restrict__ rc, float* __restrict__ out) {
  float S = sums[0], SS = sums[1];
  float nb = (float)BATCH;
  float bm = S / nb;
  float bm2 = SS - nb * bm * bm;
  float cnt = rc[0];
  float newc = cnt + nb;
  float delta = bm - rm[0];
  float newmean = rm[0] + delta * nb / newc;
  float newm2 = rm2[0] + bm2 + delta * delta * cnt * nb / newc;
  float sd = (newc > 1.f) ? sqrtf(newm2 / (newc - 1.f)) : 1.f;
  float inv = 1.f / (sd + 1e-8f);
  int i = (blockIdx.x * 256 + threadIdx.x) * 4;
  float4 r = *(const float4*)(rewards + i);
  float4 o;
  o.x = (r.x - newmean) * inv; o.y = (r.y - newmean) * inv;
  o.z = (r.z - newmean) * inv; o.w = (r.w - newmean) * inv;
  *(float4*)(out + i) = o;
}

extern "C" void kernel_launch(void* const* d_in, const int* in_sizes, int n_in,
                              void* d_out, int out_size, void* d_ws, size_t ws_size,
                              hipStream_t stream) {
  const float* obs = (const float*)d_in[0];
  const float* rm  = (const float*)d_in[1];
  const float* rm2 = (const float*)d_in[2];
  const float* rc  = (const float*)d_in[3];
  const float* tW1 = (const float*)d_in[4];
  const float* tb1 = (const float*)d_in[5];
  const float* tW2 = (const float*)d_in[6];
  const float* tb2 = (const float*)d_in[7];
  const float* tW3 = (const float*)d_in[8];
  const float* tb3 = (const float*)d_in[9];
  const float* pW1 = (const float*)d_in[10];
  const float* pb1 = (const float*)d_in[11];
  const float* pW2 = (const float*)d_in[12];
  const float* pb2 = (const float*)d_in[13];
  const float* pW3 = (const float*)d_in[14];
  const float* pb3 = (const float*)d_in[15];

  float*    sums    = (float*)d_ws;
  float*    rewards = (float*)((char*)d_ws + 256);
  uint16_t* Wall    = (uint16_t*)((char*)d_ws + 256 + (size_t)BATCH * 4);

  (void)hipFuncSetAttribute((const void*)rnd_main,
                            hipFuncAttributeMaxDynamicSharedMemorySize, 49152);

  rnd_prep<<<40, 256, 0, stream>>>(tW1, tW2, tW3, pW1, pW2, pW3, Wall, sums);
  rnd_main<<<BATCH / 128, 256, 49152, stream>>>(obs, Wall, tb1, tb2, pb1, pb2,
                                                tb3, pb3, rewards, sums);
  rnd_norm<<<BATCH / 1024, 256, 0, stream>>>(rewards, sums, rm, rm2, rc, (float*)d_out);
}